// Round 7
// baseline (643.395 us; speedup 1.0000x reference)
//
#include <hip/hip_runtime.h>
#include <math.h>

// ---------------------------------------------------------------------------
// JKNet: 2-layer GCN (sym-norm A+I) + sum-JK + linear + log_softmax.
// Round 7: gather back to coalesced lane-geometry (1 node/wave, lane = dword
// of the 256 B bf16 row -> every row-load is one contiguous coalesced
// wave-load, the access shape r2 proved runs at 26 G loads/s), metadata from
// one eadj wave-load + shuffles, 16 independent row-loads batched per iter.
// ---------------------------------------------------------------------------

#define NPAD (1 << 17)   // padded node-array stride (N=100000)
#define CHUNK 1024       // scan chunk (elements per block)

typedef __attribute__((ext_vector_type(8))) short short8;
typedef __attribute__((ext_vector_type(4))) float f32x4;

__device__ inline unsigned short f2bf(float f) {
    unsigned u = __builtin_bit_cast(unsigned, f);
    return (unsigned short)((u + 0x7fffu + ((u >> 16) & 1u)) >> 16);
}
__device__ inline float bflo(unsigned u) { return __builtin_bit_cast(float, u << 16); }
__device__ inline float bfhi(unsigned u) { return __builtin_bit_cast(float, u & 0xffff0000u); }

// ---- CSR build ------------------------------------------------------------

__global__ void hist_kernel(const int* __restrict__ dst, int* __restrict__ cnt, int E) {
    int e = blockIdx.x * 256 + threadIdx.x;
    if (e < E) atomicAdd(&cnt[dst[e]], 1);
}

__global__ void scan_partial(const int* __restrict__ cnt, int* __restrict__ partial, int n) {
    __shared__ int sdata[4];
    int b = blockIdx.x, t = threadIdx.x;
    int base = b * CHUNK;
    int sum = 0;
    for (int i = t; i < CHUNK; i += 256) {
        int idx = base + i;
        if (idx < n) sum += cnt[idx];
    }
#pragma unroll
    for (int off = 32; off > 0; off >>= 1) sum += __shfl_down(sum, off, 64);
    if ((t & 63) == 0) sdata[t >> 6] = sum;
    __syncthreads();
    if (t == 0) partial[b] = sdata[0] + sdata[1] + sdata[2] + sdata[3];
}

__global__ void scan_small(int* partial, int nblk) {
    if (threadIdx.x == 0 && blockIdx.x == 0) {
        int acc = 0;
        for (int i = 0; i < nblk; i++) { int v = partial[i]; partial[i] = acc; acc += v; }
    }
}

__global__ void scan_final(const int* __restrict__ cnt, const int* __restrict__ partial,
                           int* __restrict__ offs, int* __restrict__ cursor,
                           float* __restrict__ dis, int n) {
    __shared__ int wsum[4];
    int b = blockIdx.x, t = threadIdx.x;
    int lane = t & 63, w = t >> 6;
    int base = b * CHUNK + t * 4;
    int v[4];
#pragma unroll
    for (int j = 0; j < 4; j++) v[j] = (base + j < n) ? cnt[base + j] : 0;
    int s4 = v[0] + v[1] + v[2] + v[3];
    int inc = s4;
#pragma unroll
    for (int off = 1; off < 64; off <<= 1) {
        int x = __shfl_up(inc, off, 64);
        if (lane >= off) inc += x;
    }
    if (lane == 63) wsum[w] = inc;
    __syncthreads();
    int woff = 0;
    for (int i = 0; i < 4; i++) if (i < w) woff += wsum[i];
    int pos = partial[b] + woff + (inc - s4);
#pragma unroll
    for (int j = 0; j < 4; j++) {
        int idx = base + j;
        if (idx < n) {
            offs[idx] = pos;
            cursor[idx] = pos;
            dis[idx] = rsqrtf((float)(v[j] + 1));  // deg = incoming + self-loop
            pos += v[j];
        }
    }
}

// Bucketed permute: edges with dst in [lo,hi) only. Stores (src, dis[s]*dis[d]).
__global__ void permute_bucket(const int* __restrict__ src, const int* __restrict__ dst,
                               const float* __restrict__ dis,
                               int* __restrict__ cursor, int2* __restrict__ eadj,
                               int E, int lo, int hi) {
    int e = blockIdx.x * 256 + threadIdx.x;
    if (e < E) {
        int d = dst[e];
        if (d >= lo && d < hi) {
            int s = src[e];
            int pos = atomicAdd(&cursor[d], 1);
            float wt = dis[s] * dis[d];
            eadj[pos] = make_int2(s, __float_as_int(wt));
        }
    }
}

// ---- W cast+transpose: Wt[n][k] = bf16(W[k][n]) ---------------------------
__global__ void wcast(const float* __restrict__ W, unsigned short* __restrict__ Wt, int K) {
    int i = blockIdx.x * 256 + threadIdx.x;
    if (i < K * 128) {
        int k = i >> 7, nn = i & 127;
        Wt[nn * K + k] = f2bf(W[i]);
    }
}

// ---- MFMA GEMM: Hb[n,128](bf16) = A[n,K] @ W[K,128] -----------------------
template<bool ABF16>
__global__ __launch_bounds__(256) void gemm_mfma(const void* __restrict__ Ap,
                                                 const unsigned short* __restrict__ Wt,
                                                 unsigned short* __restrict__ Hb,
                                                 int n, int K) {
    __shared__ unsigned short bs[128 * 136];
    const int tid = threadIdx.x;
    const int wave = tid >> 6, lane = tid & 63;
    const int quad = lane >> 4, mrow = lane & 15;
    const int arow_g = blockIdx.x * 64 + wave * 16 + mrow;
    const int arow = arow_g < n ? arow_g : n - 1;

    f32x4 acc[8];
#pragma unroll
    for (int t = 0; t < 8; t++) acc[t] = (f32x4){0.f, 0.f, 0.f, 0.f};

    const float* Af = (const float*)Ap;
    const unsigned short* Ab = (const unsigned short*)Ap;

    for (int kc = 0; kc < K; kc += 128) {
        __syncthreads();
        for (int i = tid; i < 2048; i += 256) {
            int row = i >> 4, c8 = i & 15;
            *(short8*)&bs[row * 136 + c8 * 8] = *(const short8*)&Wt[row * K + kc + c8 * 8];
        }
        __syncthreads();
#pragma unroll
        for (int kt = 0; kt < 128; kt += 32) {
            union { short8 v; unsigned short u[8]; } A;
            if (ABF16) {
                A.v = *(const short8*)&Ab[(size_t)arow * K + kc + kt + quad * 8];
            } else {
                const float* ap = &Af[(size_t)arow * K + kc + kt + quad * 8];
                float4 p0 = *(const float4*)ap;
                float4 p1 = *(const float4*)(ap + 4);
                A.u[0] = f2bf(p0.x); A.u[1] = f2bf(p0.y);
                A.u[2] = f2bf(p0.z); A.u[3] = f2bf(p0.w);
                A.u[4] = f2bf(p1.x); A.u[5] = f2bf(p1.y);
                A.u[6] = f2bf(p1.z); A.u[7] = f2bf(p1.w);
            }
#pragma unroll
            for (int nt = 0; nt < 8; nt++) {
                short8 B = *(const short8*)&bs[(nt * 16 + mrow) * 136 + kt + quad * 8];
                acc[nt] = __builtin_amdgcn_mfma_f32_16x16x32_bf16(A.v, B, acc[nt], 0, 0, 0);
            }
        }
    }
    const int drow0 = blockIdx.x * 64 + wave * 16 + quad * 4;
#pragma unroll
    for (int r = 0; r < 4; r++) {
        int dr = drow0 + r;
        if (dr < n) {
#pragma unroll
            for (int nt = 0; nt < 8; nt++)
                Hb[(size_t)dr * 128 + nt * 16 + mrow] = f2bf(acc[nt][r]);
        }
    }
}

// ---- CSR gather (+optional fused JK head) ---------------------------------
// Wave = 1 node; lane = dword index into the 256 B bf16 row (features 2l,2l+1).
// One wave-load of eadj grabs <=64 edges' (src,weight); per-edge values come
// from shuffles. 16 row-loads per batch, all issued before any FMA — each is
// one contiguous coalesced 256 B wave-load. Tail lanes clamp to edge c-1 with
// weight 0: loads dup a cached row (free), math unaffected, no branches.
template<bool FUSE>
__global__ __launch_bounds__(256) void gather_k(const unsigned short* __restrict__ Hb,
                                                const int2* __restrict__ eadj,
                                                const int* __restrict__ offs,
                                                const int* __restrict__ cnt,
                                                const float* __restrict__ dis,
                                                const float* __restrict__ bias,
                                                unsigned short* __restrict__ outb,
                                                const unsigned short* __restrict__ x1b,
                                                const float* __restrict__ lw,
                                                const float* __restrict__ lb,
                                                float* __restrict__ out, int n) {
    __shared__ float s[4][128];
    const int w = threadIdx.x >> 6, lane = threadIdx.x & 63;
    const int node = blockIdx.x * 4 + w;
    const int nd = node < n ? node : n - 1;
    const int st = offs[nd], c = cnt[nd];
    const unsigned* Hu = (const unsigned*)Hb;    // row = 64 dwords = 256 B

    float a0 = 0.f, a1 = 0.f;

    const int2* ep = eadj + st;
    for (int kk = 0; kk < c; kk += 64) {
        int li = kk + lane;
        int2 me = ep[li < c ? li : c - 1];        // c > 0 inside loop
        float mw = li < c ? __int_as_float(me.y) : 0.f;
        int cend = (c - kk) < 64 ? (c - kk) : 64;

        for (int j = 0; j < cend; j += 16) {
            unsigned u[16];
            float wv[16];
#pragma unroll
            for (int k = 0; k < 16; k++) {
                int sk = __shfl(me.x, j + k, 64);
                wv[k]  = __shfl(mw,  j + k, 64);
                u[k] = Hu[(size_t)sk * 64 + lane];
            }
#pragma unroll
            for (int k = 0; k < 16; k++) {
                a0 = fmaf(bflo(u[k]), wv[k], a0);
                a1 = fmaf(bfhi(u[k]), wv[k], a1);
            }
        }
    }

    // self-loop + bias + relu
    float dd = dis[nd], sn = dd * dd;
    unsigned us = Hu[(size_t)nd * 64 + lane];
    float2 bb = ((const float2*)bias)[lane];
    a0 = fmaf(bflo(us), sn, a0) + bb.x;
    a1 = fmaf(bfhi(us), sn, a1) + bb.y;
    a0 = a0 > 0.f ? a0 : 0.f;
    a1 = a1 > 0.f ? a1 : 0.f;

    if (!FUSE) {
        if (node < n) {
            unsigned pk = ((unsigned)f2bf(a1) << 16) | (unsigned)f2bf(a0);
            ((unsigned*)outb)[(size_t)node * 64 + lane] = pk;
        }
    } else {
        unsigned xu = ((const unsigned*)x1b)[(size_t)nd * 64 + lane];
        s[w][2 * lane]     = a0 + bflo(xu);
        s[w][2 * lane + 1] = a1 + bfhi(xu);
        __syncthreads();
        bool act = (node < n) && (lane < 41);
        float val = 0.f;
        if (act) {
#pragma unroll 4
            for (int f = 0; f < 128; f++) val = fmaf(s[w][f], lw[f * 41 + lane], val);
            val += lb[lane];
        }
        float m = act ? val : -INFINITY;
#pragma unroll
        for (int off = 32; off > 0; off >>= 1) m = fmaxf(m, __shfl_xor(m, off, 64));
        float e = act ? expf(val - m) : 0.f;
#pragma unroll
        for (int off = 32; off > 0; off >>= 1) e += __shfl_xor(e, off, 64);
        if (act) out[(size_t)node * 41 + lane] = val - m - logf(e);
    }
}

extern "C" void kernel_launch(void* const* d_in, const int* in_sizes, int n_in,
                              void* d_out, int out_size, void* d_ws, size_t ws_size,
                              hipStream_t stream) {
    const float* x  = (const float*)d_in[0];
    const int*   ei = (const int*)d_in[1];
    const float* W1 = (const float*)d_in[2];
    const float* b1 = (const float*)d_in[3];
    const float* W2 = (const float*)d_in[4];
    const float* b2 = (const float*)d_in[5];
    const float* lw = (const float*)d_in[6];
    const float* lb = (const float*)d_in[7];
    float* out = (float*)d_out;

    const int n = in_sizes[0] / 256;   // 100000
    const int E = in_sizes[1] / 2;     // 1600000
    const int* src = ei;
    const int* dst = ei + E;

    // workspace layout
    int*   cnt     = (int*)d_ws;                       // NPAD
    int*   offs    = cnt + NPAD;                       // NPAD
    int*   cursor  = offs + NPAD;                      // NPAD
    int*   partial = cursor + NPAD;                    // 1024
    float* dis     = (float*)(partial + 1024);         // NPAD
    size_t Epad    = ((size_t)E + 255) & ~(size_t)255;
    int2*  eadj    = (int2*)(dis + NPAD);              // Epad pairs (8 B)
    unsigned short* Wt1 = (unsigned short*)(eadj + Epad);  // 256*128 bf16
    unsigned short* Wt2 = Wt1 + 256 * 128;                 // 128*128 bf16
    unsigned short* Hb  = Wt2 + 128 * 128;                 // n*128 bf16
    unsigned short* X1b = Hb + (size_t)n * 128;            // n*128 bf16

    const int nscan = (n + CHUNK - 1) / CHUNK;

    hipMemsetAsync(cnt, 0, (size_t)n * sizeof(int), stream);
    wcast<<<(256 * 128 + 255) / 256, 256, 0, stream>>>(W1, Wt1, 256);
    wcast<<<(128 * 128 + 255) / 256, 256, 0, stream>>>(W2, Wt2, 128);

    // CSR build (reused by both layers)
    hist_kernel<<<(E + 255) / 256, 256, 0, stream>>>(dst, cnt, E);
    scan_partial<<<nscan, 256, 0, stream>>>(cnt, partial, n);
    scan_small<<<1, 64, 0, stream>>>(partial, nscan);
    scan_final<<<nscan, 256, 0, stream>>>(cnt, partial, offs, cursor, dis, n);
    {
        const int NBUCKET = 2;
        int W = (n + NBUCKET - 1) / NBUCKET;
        for (int p = 0; p < NBUCKET; p++) {
            int lo = p * W, hi = lo + W < n ? lo + W : n;
            permute_bucket<<<(E + 255) / 256, 256, 0, stream>>>(src, dst, dis, cursor, eadj, E, lo, hi);
        }
    }

    // layer 1: h = bf16(x @ W1); x1 = relu(agg) (bf16)
    gemm_mfma<false><<<(n + 63) / 64, 256, 0, stream>>>(x, Wt1, Hb, n, 256);
    gather_k<false><<<(n + 3) / 4, 256, 0, stream>>>(Hb, eadj, offs, cnt, dis, b1, X1b,
                                                     nullptr, nullptr, nullptr, nullptr, n);

    // layer 2 + fused JK head
    gemm_mfma<true><<<(n + 63) / 64, 256, 0, stream>>>(X1b, Wt2, Hb, n, 128);
    gather_k<true><<<(n + 3) / 4, 256, 0, stream>>>(Hb, eadj, offs, cnt, dis, b2, nullptr,
                                                    X1b, lw, lb, out, n);
}